// Round 2
// baseline (125.188 us; speedup 1.0000x reference)
//
#include <hip/hip_runtime.h>
#include <math.h>

#define N_HIT  50000
#define N_TRUE 512
#define N_EDGE 40000
#define Q_MIN  0.5f

// ---- ws layout (4-byte word offsets) ----
#define W_CENTERS 512        // [512,1024)  int centers, zeroed by A
#define W_SUMFC   1024       // float
#define W_SUMBKG  1025       // float
#define W_NBKG    1026       // uint
#define W_DONE    1027       // uint done-counter
#define W_VPART   1040       // 8 float slots, stride 16 words (64B apart)
#define W_ZERO_LO 512        // A zeroes [512, 1168)
#define W_ZERO_HI 1168
#define W_FCPART  2048       // uint fc_part[16][512]
#define W_CTAB    10240      // float ctab[512][12]  (x0..x7, qc, pad)
#define W_MASK    16384      // uint mask[50000][16]
#define MASK_WPH  16
#define MASK_U4   (N_HIT * MASK_WPH / 4)   // 200000 uint4

#define A_EDGE_BLOCKS 16
#define EDGES_PER_BLOCK (N_EDGE / A_EDGE_BLOCKS)   // 2500
#define A_GRID 256

#define D_BLOCK 128
#define D_HB ((N_HIT + D_BLOCK - 1) / D_BLOCK)     // 391
#define D_GRID (D_HB * 2)                          // 782

// A: privatized segment-max partials (no global atomics) + zero mask/scalars
__global__ __launch_bounds__(256) void k_prep(const float* __restrict__ f,
                                              const int* __restrict__ e_h,
                                              const int* __restrict__ e_p,
                                              unsigned* __restrict__ ws) {
    const int b = blockIdx.x, t = threadIdx.x;
    if (b < A_EDGE_BLOCKS) {
        __shared__ unsigned lmax[N_TRUE];
        lmax[t] = 0u; lmax[t + 256] = 0u;
        __syncthreads();
        const int e0 = b * EDGES_PER_BLOCK;
        for (int e = e0 + t; e < e0 + EDGES_PER_BLOCK; e += 256)
            atomicMax(&lmax[e_p[e]], __float_as_uint(f[e_h[e]]));
        __syncthreads();
        ws[W_FCPART + b * N_TRUE + t]       = lmax[t];
        ws[W_FCPART + b * N_TRUE + t + 256] = lmax[t + 256];
    } else {
        const int zb = b - A_EDGE_BLOCKS;
        if (zb == 0)
            for (int w = W_ZERO_LO + t; w < W_ZERO_HI; w += 256) ws[w] = 0u;
        uint4* m4 = (uint4*)(ws + W_MASK);
        const int nthr = (A_GRID - A_EDGE_BLOCKS) * 256;
        for (int idx = zb * 256 + t; idx < MASK_U4; idx += nthr)
            m4[idx] = make_uint4(0u, 0u, 0u, 0u);
    }
}

// B: per edge — rebuild segment max from partials, argmax-hit, membership bits
__global__ __launch_bounds__(256) void k_edge(const float* __restrict__ f,
                                              const int* __restrict__ e_h,
                                              const int* __restrict__ e_p,
                                              unsigned* __restrict__ ws) {
    const int e = blockIdx.x * 256 + threadIdx.x;
    if (e >= N_EDGE) return;
    const int h = e_h[e], p = e_p[e];
    unsigned fm = 0u;
#pragma unroll
    for (int b = 0; b < A_EDGE_BLOCKS; ++b)
        fm = max(fm, ws[W_FCPART + b * N_TRUE + p]);
    if (__float_as_uint(f[h]) == fm)
        atomicMax((int*)ws + W_CENTERS + p, h);
    atomicOr(&ws[W_MASK + (size_t)h * MASK_WPH + (p >> 5)], 1u << (p & 31));
}

// C: block 0 packs center table + f_centers sum; blocks 1..16 do bkg sums
__global__ __launch_bounds__(256) void k_scal(const float* __restrict__ x,
                                              const float* __restrict__ f,
                                              const int* __restrict__ y,
                                              unsigned* __restrict__ ws) {
    const int b = blockIdx.x, t = threadIdx.x;
    __shared__ float r2[8];
    if (b == 0) {
        float local = 0.f;
        for (int p = t; p < N_TRUE; p += 256) {
            unsigned fm = 0u;
#pragma unroll
            for (int bb = 0; bb < A_EDGE_BLOCKS; ++bb)
                fm = max(fm, ws[W_FCPART + bb * N_TRUE + p]);
            local += __uint_as_float(fm);
            const int c = ((const int*)ws)[W_CENTERS + p];
            float* ct = (float*)ws + W_CTAB + p * 12;
            const float4* xp = (const float4*)(x + (size_t)c * 8);
            ((float4*)ct)[0] = xp[0];
            ((float4*)ct)[1] = xp[1];
            const float a = atanhf(f[c]);
            ct[8] = fmaf(a, a, Q_MIN);
        }
        for (int off = 32; off; off >>= 1) local += __shfl_down(local, off, 64);
        if ((t & 63) == 0) r2[t >> 6] = local;
        __syncthreads();
        if (t == 0) ((float*)ws)[W_SUMFC] = r2[0] + r2[1] + r2[2] + r2[3];
    } else {
        float sf = 0.f, fc = 0.f;
        for (int i = (b - 1) * 256 + t; i < N_HIT; i += 16 * 256) {
            if (y[i] == -1) { sf += f[i]; fc += 1.f; }
        }
        for (int off = 32; off; off >>= 1) {
            sf += __shfl_down(sf, off, 64);
            fc += __shfl_down(fc, off, 64);
        }
        if ((t & 63) == 0) { r2[t >> 6] = sf; r2[4 + (t >> 6)] = fc; }
        __syncthreads();
        if (t == 0) {
            atomicAdd((float*)ws + W_SUMBKG, r2[0] + r2[1] + r2[2] + r2[3]);
            atomicAdd(&ws[W_NBKG], (unsigned)(r2[4] + r2[5] + r2[6] + r2[7]));
        }
    }
}

// D: dense pair loop, L1-broadcast center table, fused finalize
__global__ __launch_bounds__(D_BLOCK) void k_main(const float* __restrict__ x,
                                                  const float* __restrict__ f,
                                                  unsigned* __restrict__ ws,
                                                  float* __restrict__ out) {
    const int t  = threadIdx.x;
    const int hb = blockIdx.x >> 1;
    const int kb = blockIdx.x & 1;
    const int k0 = kb * 256;
    const int i  = hb * D_BLOCK + t;
    const float* ctab = (const float*)ws + W_CTAB;
    float vout = 0.f;
    if (i < N_HIT) {
        const float4* xp = (const float4*)(x + (size_t)i * 8);
        const float4 a0 = xp[0], a1 = xp[1];
        const float at = atanhf(f[i]);
        const float qi = fmaf(at, at, Q_MIN);
        const unsigned* mrow = ws + W_MASK + (size_t)i * MASK_WPH + kb * 8;
        float acc = 0.f;
        for (int w = 0; w < 8; ++w) {
            const unsigned word = mrow[w];
            const float* ctw = ctab + (size_t)(k0 + w * 32) * 12;
#pragma unroll 8
            for (int k2 = 0; k2 < 32; ++k2) {
                const float4 c0 = *(const float4*)(ctw + 12 * k2);
                const float4 c1 = *(const float4*)(ctw + 12 * k2 + 4);
                const float qck = ctw[12 * k2 + 8];
                float d, dist;
                d = a0.x - c0.x; dist = d * d;
                d = a0.y - c0.y; dist = fmaf(d, d, dist);
                d = a0.z - c0.z; dist = fmaf(d, d, dist);
                d = a0.w - c0.w; dist = fmaf(d, d, dist);
                d = a1.x - c1.x; dist = fmaf(d, d, dist);
                d = a1.y - c1.y; dist = fmaf(d, d, dist);
                d = a1.z - c1.z; dist = fmaf(d, d, dist);
                d = a1.w - c1.w; dist = fmaf(d, d, dist);
                const float rep = fmaxf(1.f - dist, 0.f);
                const float sel = ((word >> k2) & 1u) ? dist : rep;
                acc = fmaf(sel, qck, acc);
            }
        }
        vout = acc * qi;
    }
    for (int off = 32; off; off >>= 1) vout += __shfl_down(vout, off, 64);
    __shared__ float r[2];
    if ((t & 63) == 0) r[t >> 6] = vout;
    __syncthreads();
    if (t == 0) {
        atomicAdd((float*)ws + W_VPART + (blockIdx.x & 7) * 16, r[0] + r[1]);
        __threadfence();
        const unsigned c = atomicAdd(&ws[W_DONE], 1u);
        if (c == D_GRID - 1) {
            __threadfence();
            float vs = 0.f;
            for (int s = 0; s < 8; ++s)
                vs += atomicAdd((float*)ws + W_VPART + s * 16, 0.0f);
            const float sum_fc  = ((const float*)ws)[W_SUMFC];
            const float sum_bkg = ((const float*)ws)[W_SUMBKG];
            const float nb = (float)ws[W_NBKG];
            out[0] = (1.f - sum_fc / (float)N_TRUE) + sum_bkg / nb;  // S_B = 1
            out[1] = vs / (float)N_HIT;
        }
    }
}

extern "C" void kernel_launch(void* const* d_in, const int* in_sizes, int n_in,
                              void* d_out, int out_size, void* d_ws, size_t ws_size,
                              hipStream_t stream) {
    const float* x   = (const float*)d_in[0];
    const float* f   = (const float*)d_in[1];
    const int*   y   = (const int*)d_in[2];
    const int*   e_h = (const int*)d_in[3];
    const int*   e_p = (const int*)d_in[4];
    float* out = (float*)d_out;
    unsigned* ws = (unsigned*)d_ws;

    k_prep<<<A_GRID, 256, 0, stream>>>(f, e_h, e_p, ws);
    k_edge<<<(N_EDGE + 255) / 256, 256, 0, stream>>>(f, e_h, e_p, ws);
    k_scal<<<17, 256, 0, stream>>>(x, f, y, ws);
    k_main<<<D_GRID, D_BLOCK, 0, stream>>>(x, f, ws, out);
}

// Round 3
// 120.149 us; speedup vs baseline: 1.0419x; 1.0419x over previous
//
#include <hip/hip_runtime.h>
#include <math.h>

#define N_HIT  50000
#define N_TRUE 512
#define N_EDGE 40000
#define Q_MIN  0.5f

// ---- ws layout (4-byte word offsets) ----
#define W_CENTERS   512           // int[512], zeroed by k_prep
#define W_SUMFC     1024          // float, written by k_edge tail
#define W_DONE_EDGE 1025          // uint, zeroed by k_prep
#define W_DONE_MAIN 1026          // uint, zeroed by k_prep
#define W_VPART     1040          // 8 float slots, stride 16 words
#define W_ZERO_LO   512
#define W_ZERO_HI   1168
#define W_BKGPART   1200          // float[16] sum_f_bkg partials (unconditionally written)
#define W_BKGCNT    1216          // float[16] n_bkg partials
#define W_FCPART    2048          // uint fc_part[16][512]
#define W_CTAB      16384         // float ctab[512][16]: c0..c7, |c|^2, qc, pad  (64B lines)
#define W_MASK      24576         // uint mask[50000][16]
#define MASK_WPH  16
#define MASK_U4   (N_HIT * MASK_WPH / 4)

#define A_EDGE_BLOCKS 16
#define A_BKG_BLOCKS  16
#define EPB (N_EDGE / A_EDGE_BLOCKS)    // 2500
#define A_GRID 256

#define E_GRID ((N_EDGE + 255) / 256)   // 157

#define KSPLIT 8
#define KCH    (N_TRUE / KSPLIT)        // 64
#define D_HB   ((N_HIT + 255) / 256)    // 196
#define D_GRID (D_HB * KSPLIT)          // 1568

// A: segment-max partials (LDS-privatized), bkg sums, zero mask/scalars
__global__ __launch_bounds__(256) void k_prep(const float* __restrict__ f,
                                              const int* __restrict__ e_h,
                                              const int* __restrict__ e_p,
                                              const int* __restrict__ y,
                                              unsigned* __restrict__ ws) {
    const int b = blockIdx.x, t = threadIdx.x;
    if (b < A_EDGE_BLOCKS) {
        __shared__ unsigned lmax[N_TRUE];
        lmax[t] = 0u; lmax[t + 256] = 0u;
        __syncthreads();
        const int e0 = b * EPB;
        for (int e = e0 + t; e < e0 + EPB; e += 256)
            atomicMax(&lmax[e_p[e]], __float_as_uint(f[e_h[e]]));
        __syncthreads();
        ws[W_FCPART + b * N_TRUE + t]       = lmax[t];
        ws[W_FCPART + b * N_TRUE + t + 256] = lmax[t + 256];
    } else if (b < A_EDGE_BLOCKS + A_BKG_BLOCKS) {
        const int bb = b - A_EDGE_BLOCKS;
        float sf = 0.f, fc = 0.f;
        for (int i = bb * 256 + t; i < N_HIT; i += A_BKG_BLOCKS * 256)
            if (y[i] == -1) { sf += f[i]; fc += 1.f; }
        for (int off = 32; off; off >>= 1) {
            sf += __shfl_down(sf, off, 64);
            fc += __shfl_down(fc, off, 64);
        }
        __shared__ float r[8];
        if ((t & 63) == 0) { r[t >> 6] = sf; r[4 + (t >> 6)] = fc; }
        __syncthreads();
        if (t == 0) {
            ((float*)ws)[W_BKGPART + bb] = r[0] + r[1] + r[2] + r[3];
            ((float*)ws)[W_BKGCNT  + bb] = r[4] + r[5] + r[6] + r[7];
        }
    } else {
        const int zb = b - A_EDGE_BLOCKS - A_BKG_BLOCKS;   // 0..223
        if (zb == 0)
            for (int w = W_ZERO_LO + t; w < W_ZERO_HI; w += 256) ws[w] = 0u;
        uint4* m4 = (uint4*)(ws + W_MASK);
        const int nthr = (A_GRID - A_EDGE_BLOCKS - A_BKG_BLOCKS) * 256;
        for (int idx = zb * 256 + t; idx < MASK_U4; idx += nthr)
            m4[idx] = make_uint4(0u, 0u, 0u, 0u);
    }
}

// B: per edge — argmax-hit + membership bits; last block builds center table
__global__ __launch_bounds__(256) void k_edge(const float* __restrict__ x,
                                              const float* __restrict__ f,
                                              const int* __restrict__ e_h,
                                              const int* __restrict__ e_p,
                                              unsigned* __restrict__ ws) {
    const int t = threadIdx.x;
    const int e = blockIdx.x * 256 + t;
    if (e < N_EDGE) {
        const int h = e_h[e], p = e_p[e];
        unsigned fm = 0u;
#pragma unroll
        for (int b = 0; b < A_EDGE_BLOCKS; ++b)
            fm = max(fm, ws[W_FCPART + b * N_TRUE + p]);
        if (__float_as_uint(f[h]) == fm)
            atomicMax((int*)ws + W_CENTERS + p, h);
        atomicOr(&ws[W_MASK + (size_t)h * MASK_WPH + (p >> 5)], 1u << (p & 31));
    }
    __syncthreads();
    __shared__ int is_last;
    if (t == 0) {
        __threadfence();
        is_last = (atomicAdd(&ws[W_DONE_EDGE], 1u) == E_GRID - 1);
    }
    __syncthreads();
    if (!is_last) return;

    // tail: all centers/atomics globally done — build ctab + sum f_centers
    __threadfence();
    float local = 0.f;
    for (int p = t; p < N_TRUE; p += 256) {
        unsigned fm = 0u;
#pragma unroll
        for (int b = 0; b < A_EDGE_BLOCKS; ++b)
            fm = max(fm, ws[W_FCPART + b * N_TRUE + p]);
        local += __uint_as_float(fm);
        const int c = __hip_atomic_load((int*)ws + W_CENTERS + p,
                                        __ATOMIC_RELAXED, __HIP_MEMORY_SCOPE_AGENT);
        const float4* xp = (const float4*)(x + (size_t)c * 8);
        const float4 x0 = xp[0], x1 = xp[1];
        float ck2 = x0.x * x0.x;
        ck2 = fmaf(x0.y, x0.y, ck2); ck2 = fmaf(x0.z, x0.z, ck2);
        ck2 = fmaf(x0.w, x0.w, ck2); ck2 = fmaf(x1.x, x1.x, ck2);
        ck2 = fmaf(x1.y, x1.y, ck2); ck2 = fmaf(x1.z, x1.z, ck2);
        ck2 = fmaf(x1.w, x1.w, ck2);
        const float a = atanhf(f[c]);
        float* line = (float*)ws + W_CTAB + (size_t)p * 16;
        ((float4*)line)[0] = x0;
        ((float4*)line)[1] = x1;
        line[8] = ck2;
        line[9] = fmaf(a, a, Q_MIN);
    }
    for (int off = 32; off; off >>= 1) local += __shfl_down(local, off, 64);
    __shared__ float r[4];
    if ((t & 63) == 0) r[t >> 6] = local;
    __syncthreads();
    if (t == 0) ((float*)ws)[W_SUMFC] = r[0] + r[1] + r[2] + r[3];
}

// C: dense pair loop + fused finalize
__global__ __launch_bounds__(256) void k_main(const float* __restrict__ x,
                                              const float* __restrict__ f,
                                              unsigned* __restrict__ ws,
                                              float* __restrict__ out) {
    const int t  = threadIdx.x;
    const int hb = blockIdx.x >> 3;
    const int kb = blockIdx.x & 7;
    const int i  = hb * 256 + t;
    const float* __restrict__ ctab = (const float*)ws + W_CTAB;
    float vout = 0.f;
    if (i < N_HIT) {
        const float4* xp = (const float4*)(x + (size_t)i * 8);
        const float4 a0 = xp[0], a1 = xp[1];
        float xi2 = a0.x * a0.x;
        xi2 = fmaf(a0.y, a0.y, xi2); xi2 = fmaf(a0.z, a0.z, xi2);
        xi2 = fmaf(a0.w, a0.w, xi2); xi2 = fmaf(a1.x, a1.x, xi2);
        xi2 = fmaf(a1.y, a1.y, xi2); xi2 = fmaf(a1.z, a1.z, xi2);
        xi2 = fmaf(a1.w, a1.w, xi2);
        const float at = atanhf(f[i]);
        const float qi = fmaf(at, at, Q_MIN);
        const uint2 m = *(const uint2*)(ws + W_MASK + (size_t)i * MASK_WPH + kb * 2);
        float acc = 0.f;
#pragma unroll
        for (int w = 0; w < 2; ++w) {
            const unsigned word = w ? m.y : m.x;
            const float* __restrict__ ctw = ctab + (size_t)(kb * KCH + w * 32) * 16;
#pragma unroll 8
            for (int k2 = 0; k2 < 32; ++k2) {
                const float4 c0 = *(const float4*)(ctw + 16 * k2);
                const float4 c1 = *(const float4*)(ctw + 16 * k2 + 4);
                const float ck2 = ctw[16 * k2 + 8];
                const float qck = ctw[16 * k2 + 9];
                float dot = a0.x * c0.x;
                dot = fmaf(a0.y, c0.y, dot); dot = fmaf(a0.z, c0.z, dot);
                dot = fmaf(a0.w, c0.w, dot); dot = fmaf(a1.x, c1.x, dot);
                dot = fmaf(a1.y, c1.y, dot); dot = fmaf(a1.z, c1.z, dot);
                dot = fmaf(a1.w, c1.w, dot);
                const float dist = fmaf(-2.f, dot, xi2 + ck2);
                const float rep  = fmaxf(1.f - dist, 0.f);
                const float sel  = ((word >> k2) & 1u) ? dist : rep;
                acc = fmaf(sel, qck, acc);
            }
        }
        vout = acc * qi;
    }
    for (int off = 32; off; off >>= 1) vout += __shfl_down(vout, off, 64);
    __shared__ float r[4];
    if ((t & 63) == 0) r[t >> 6] = vout;
    __syncthreads();
    if (t == 0) {
        atomicAdd((float*)ws + W_VPART + (blockIdx.x & 7) * 16, r[0] + r[1] + r[2] + r[3]);
        __threadfence();
        const unsigned c = atomicAdd(&ws[W_DONE_MAIN], 1u);
        if (c == D_GRID - 1) {
            __threadfence();
            float vs = 0.f;
            for (int s = 0; s < 8; ++s)
                vs += atomicAdd((float*)ws + W_VPART + s * 16, 0.0f);
            float sum_bkg = 0.f, nb = 0.f;
            for (int s = 0; s < 16; ++s) {
                sum_bkg += __hip_atomic_load((const float*)ws + W_BKGPART + s,
                                             __ATOMIC_RELAXED, __HIP_MEMORY_SCOPE_AGENT);
                nb      += __hip_atomic_load((const float*)ws + W_BKGCNT + s,
                                             __ATOMIC_RELAXED, __HIP_MEMORY_SCOPE_AGENT);
            }
            const float sum_fc = __hip_atomic_load((const float*)ws + W_SUMFC,
                                                   __ATOMIC_RELAXED, __HIP_MEMORY_SCOPE_AGENT);
            out[0] = (1.f - sum_fc / (float)N_TRUE) + sum_bkg / nb;   // S_B = 1
            out[1] = vs / (float)N_HIT;
        }
    }
}

extern "C" void kernel_launch(void* const* d_in, const int* in_sizes, int n_in,
                              void* d_out, int out_size, void* d_ws, size_t ws_size,
                              hipStream_t stream) {
    const float* x   = (const float*)d_in[0];
    const float* f   = (const float*)d_in[1];
    const int*   y   = (const int*)d_in[2];
    const int*   e_h = (const int*)d_in[3];
    const int*   e_p = (const int*)d_in[4];
    float* out = (float*)d_out;
    unsigned* ws = (unsigned*)d_ws;

    k_prep<<<A_GRID, 256, 0, stream>>>(f, e_h, e_p, y, ws);
    k_edge<<<E_GRID, 256, 0, stream>>>(x, f, e_h, e_p, ws);
    k_main<<<D_GRID, 256, 0, stream>>>(x, f, ws, out);
}

// Round 4
// 111.652 us; speedup vs baseline: 1.1212x; 1.0761x over previous
//
#include <hip/hip_runtime.h>
#include <math.h>

#define N_HIT  50000
#define N_TRUE 512
#define N_EDGE 40000
#define Q_MIN  0.5f

// ---- ws layout (4-byte word offsets) ----
#define W_CENTERS   512           // int[512], zeroed by k_prep
#define W_SUMFC     1024          // float, written by k_edge tail
#define W_DONE_EDGE 1025
#define W_DONE_MAIN 1026
#define W_VPART     1040          // 8 float slots, stride 16 words
#define W_ZERO_LO   512
#define W_ZERO_HI   1168
#define W_BKGPART   1200          // float[32]
#define W_BKGCNT    1232          // float[32]
#define W_FCPART    2048          // uint fc_part[16][512]
#define W_CTAB      16384         // float ctab[512][12]: c0..c7, |c|^2, qc, pad,pad
#define W_MASK      24576         // uint mask[50000][16]
#define W_HREC      825344        // float2 hrec[50000]: (|x|^2, q)
#define MASK_WPH  16
#define MASK_U4   (N_HIT * MASK_WPH / 4)

#define A_EDGE_BLOCKS 16
#define A_BKG_BLOCKS  32
#define A_ZERO_BLOCKS 224
#define A_GRID (A_EDGE_BLOCKS + A_BKG_BLOCKS + A_ZERO_BLOCKS)   // 272
#define EPB (N_EDGE / A_EDGE_BLOCKS)    // 2500

#define E_GRID ((N_EDGE + 255) / 256)   // 157

#define KSPLIT 32
#define KCH    (N_TRUE / KSPLIT)        // 16
#define HPT    8                        // hits per thread
#define HCHUNK (256 * HPT)              // 2048
#define NHB    ((N_HIT + HCHUNK - 1) / HCHUNK)   // 25
#define D_GRID (NHB * KSPLIT)           // 800

// A: segment-max partials, bkg sums + per-hit (|x|^2,q) records, zero mask/scalars
__global__ __launch_bounds__(256) void k_prep(const float* __restrict__ x,
                                              const float* __restrict__ f,
                                              const int* __restrict__ e_h,
                                              const int* __restrict__ e_p,
                                              const int* __restrict__ y,
                                              unsigned* __restrict__ ws) {
    const int b = blockIdx.x, t = threadIdx.x;
    if (b < A_EDGE_BLOCKS) {
        __shared__ unsigned lmax[N_TRUE];
        lmax[t] = 0u; lmax[t + 256] = 0u;
        __syncthreads();
        const int e0 = b * EPB;
        for (int e = e0 + t; e < e0 + EPB; e += 256)
            atomicMax(&lmax[e_p[e]], __float_as_uint(f[e_h[e]]));
        __syncthreads();
        ws[W_FCPART + b * N_TRUE + t]       = lmax[t];
        ws[W_FCPART + b * N_TRUE + t + 256] = lmax[t + 256];
    } else if (b < A_EDGE_BLOCKS + A_BKG_BLOCKS) {
        const int bb = b - A_EDGE_BLOCKS;
        float2* hrec = (float2*)(ws + W_HREC);
        float sf = 0.f, fc = 0.f;
        for (int i = bb * 256 + t; i < N_HIT; i += A_BKG_BLOCKS * 256) {
            const float4* xp = (const float4*)(x + (size_t)i * 8);
            const float4 x0 = xp[0], x1 = xp[1];
            float xi2 = x0.x * x0.x;
            xi2 = fmaf(x0.y, x0.y, xi2); xi2 = fmaf(x0.z, x0.z, xi2);
            xi2 = fmaf(x0.w, x0.w, xi2); xi2 = fmaf(x1.x, x1.x, xi2);
            xi2 = fmaf(x1.y, x1.y, xi2); xi2 = fmaf(x1.z, x1.z, xi2);
            xi2 = fmaf(x1.w, x1.w, xi2);
            const float fi = f[i];
            const float a  = atanhf(fi);
            hrec[i] = make_float2(xi2, fmaf(a, a, Q_MIN));
            if (y[i] == -1) { sf += fi; fc += 1.f; }
        }
        for (int off = 32; off; off >>= 1) {
            sf += __shfl_down(sf, off, 64);
            fc += __shfl_down(fc, off, 64);
        }
        __shared__ float r[8];
        if ((t & 63) == 0) { r[t >> 6] = sf; r[4 + (t >> 6)] = fc; }
        __syncthreads();
        if (t == 0) {
            ((float*)ws)[W_BKGPART + bb] = r[0] + r[1] + r[2] + r[3];
            ((float*)ws)[W_BKGCNT  + bb] = r[4] + r[5] + r[6] + r[7];
        }
    } else {
        const int zb = b - A_EDGE_BLOCKS - A_BKG_BLOCKS;
        if (zb == 0)
            for (int w = W_ZERO_LO + t; w < W_ZERO_HI; w += 256) ws[w] = 0u;
        uint4* m4 = (uint4*)(ws + W_MASK);
        const int nthr = A_ZERO_BLOCKS * 256;
        for (int idx = zb * 256 + t; idx < MASK_U4; idx += nthr)
            m4[idx] = make_uint4(0u, 0u, 0u, 0u);
    }
}

// B: per edge — argmax-hit + membership bits; last block builds center table
__global__ __launch_bounds__(256) void k_edge(const float* __restrict__ x,
                                              const float* __restrict__ f,
                                              const int* __restrict__ e_h,
                                              const int* __restrict__ e_p,
                                              unsigned* __restrict__ ws) {
    const int t = threadIdx.x;
    const int e = blockIdx.x * 256 + t;
    if (e < N_EDGE) {
        const int h = e_h[e], p = e_p[e];
        unsigned fm = 0u;
#pragma unroll
        for (int b = 0; b < A_EDGE_BLOCKS; ++b)
            fm = max(fm, ws[W_FCPART + b * N_TRUE + p]);
        if (__float_as_uint(f[h]) == fm)
            atomicMax((int*)ws + W_CENTERS + p, h);
        atomicOr(&ws[W_MASK + (size_t)h * MASK_WPH + (p >> 5)], 1u << (p & 31));
    }
    __syncthreads();
    __shared__ int is_last;
    if (t == 0) {
        __threadfence();
        is_last = (atomicAdd(&ws[W_DONE_EDGE], 1u) == E_GRID - 1);
    }
    __syncthreads();
    if (!is_last) return;

    __threadfence();
    float local = 0.f;
    for (int p = t; p < N_TRUE; p += 256) {
        unsigned fm = 0u;
#pragma unroll
        for (int b = 0; b < A_EDGE_BLOCKS; ++b)
            fm = max(fm, ws[W_FCPART + b * N_TRUE + p]);
        local += __uint_as_float(fm);
        const int c = __hip_atomic_load((int*)ws + W_CENTERS + p,
                                        __ATOMIC_RELAXED, __HIP_MEMORY_SCOPE_AGENT);
        const float4* xp = (const float4*)(x + (size_t)c * 8);
        const float4 x0 = xp[0], x1 = xp[1];
        float ck2 = x0.x * x0.x;
        ck2 = fmaf(x0.y, x0.y, ck2); ck2 = fmaf(x0.z, x0.z, ck2);
        ck2 = fmaf(x0.w, x0.w, ck2); ck2 = fmaf(x1.x, x1.x, ck2);
        ck2 = fmaf(x1.y, x1.y, ck2); ck2 = fmaf(x1.z, x1.z, ck2);
        ck2 = fmaf(x1.w, x1.w, ck2);
        const float a = atanhf(f[c]);
        float* line = (float*)ws + W_CTAB + (size_t)p * 12;
        ((float4*)line)[0] = x0;
        ((float4*)line)[1] = x1;
        line[8] = ck2;
        line[9] = fmaf(a, a, Q_MIN);
    }
    for (int off = 32; off; off >>= 1) local += __shfl_down(local, off, 64);
    __shared__ float r[4];
    if ((t & 63) == 0) r[t >> 6] = local;
    __syncthreads();
    if (t == 0) ((float*)ws)[W_SUMFC] = r[0] + r[1] + r[2] + r[3];
}

// C: 8-hit x 16-k register-tiled pair loop, ctab via LDS broadcast, fused finalize
__global__ __launch_bounds__(256, 4) void k_main(const float* __restrict__ x,
                                                 unsigned* __restrict__ ws,
                                                 float* __restrict__ out) {
    const int t  = threadIdx.x;
    const int hb = blockIdx.x >> 5;       // 0..24
    const int kb = blockIdx.x & 31;       // 0..31

    __shared__ float ct[KCH * 12];
    if (t < KCH * 12) ct[t] = ((const float*)ws)[W_CTAB + kb * KCH * 12 + t];
    __syncthreads();

    float4 xr0[HPT], xr1[HPT];
    float  xi2[HPT], qi[HPT], acc[HPT];
    unsigned msk[HPT];
    const float2* __restrict__ hrec = (const float2*)(ws + W_HREC);
    const int word = kb >> 1;
    const int sh   = (kb & 1) * 16;

#pragma unroll
    for (int j = 0; j < HPT; ++j) {
        const int i = hb * HCHUNK + j * 256 + t;
        const bool valid = (i < N_HIT);
        const int  ic = valid ? i : 0;
        const float4* xp = (const float4*)(x + (size_t)ic * 8);
        xr0[j] = xp[0]; xr1[j] = xp[1];
        const float2 hq = hrec[ic];
        xi2[j] = hq.x;
        qi[j]  = valid ? hq.y : 0.f;
        msk[j] = ws[W_MASK + (size_t)ic * MASK_WPH + word] >> sh;
        acc[j] = 0.f;
    }

#pragma unroll
    for (int k2 = 0; k2 < KCH; ++k2) {
        const float4 c0  = *(const float4*)(ct + 12 * k2);
        const float4 c1  = *(const float4*)(ct + 12 * k2 + 4);
        const float  ck2 = ct[12 * k2 + 8];
        const float  qck = ct[12 * k2 + 9];
#pragma unroll
        for (int j = 0; j < HPT; ++j) {
            float dot = xr0[j].x * c0.x;
            dot = fmaf(xr0[j].y, c0.y, dot); dot = fmaf(xr0[j].z, c0.z, dot);
            dot = fmaf(xr0[j].w, c0.w, dot); dot = fmaf(xr1[j].x, c1.x, dot);
            dot = fmaf(xr1[j].y, c1.y, dot); dot = fmaf(xr1[j].z, c1.z, dot);
            dot = fmaf(xr1[j].w, c1.w, dot);
            const float dist = fmaf(-2.f, dot, xi2[j] + ck2);
            const float rep  = fmaxf(1.f - dist, 0.f);
            const float sel  = ((msk[j] >> k2) & 1u) ? dist : rep;
            acc[j] = fmaf(sel, qck, acc[j]);
        }
    }

    float vout = 0.f;
#pragma unroll
    for (int j = 0; j < HPT; ++j) vout = fmaf(acc[j], qi[j], vout);

    for (int off = 32; off; off >>= 1) vout += __shfl_down(vout, off, 64);
    __shared__ float r[4];
    if ((t & 63) == 0) r[t >> 6] = vout;
    __syncthreads();
    if (t == 0) {
        atomicAdd((float*)ws + W_VPART + (blockIdx.x & 7) * 16, r[0] + r[1] + r[2] + r[3]);
        __threadfence();
        const unsigned c = atomicAdd(&ws[W_DONE_MAIN], 1u);
        if (c == D_GRID - 1) {
            __threadfence();
            float vs = 0.f;
            for (int s = 0; s < 8; ++s)
                vs += atomicAdd((float*)ws + W_VPART + s * 16, 0.0f);
            float sum_bkg = 0.f, nb = 0.f;
            for (int s = 0; s < A_BKG_BLOCKS; ++s) {
                sum_bkg += __hip_atomic_load((const float*)ws + W_BKGPART + s,
                                             __ATOMIC_RELAXED, __HIP_MEMORY_SCOPE_AGENT);
                nb      += __hip_atomic_load((const float*)ws + W_BKGCNT + s,
                                             __ATOMIC_RELAXED, __HIP_MEMORY_SCOPE_AGENT);
            }
            const float sum_fc = __hip_atomic_load((const float*)ws + W_SUMFC,
                                                   __ATOMIC_RELAXED, __HIP_MEMORY_SCOPE_AGENT);
            out[0] = (1.f - sum_fc / (float)N_TRUE) + sum_bkg / nb;   // S_B = 1
            out[1] = vs / (float)N_HIT;
        }
    }
}

extern "C" void kernel_launch(void* const* d_in, const int* in_sizes, int n_in,
                              void* d_out, int out_size, void* d_ws, size_t ws_size,
                              hipStream_t stream) {
    const float* x   = (const float*)d_in[0];
    const float* f   = (const float*)d_in[1];
    const int*   y   = (const int*)d_in[2];
    const int*   e_h = (const int*)d_in[3];
    const int*   e_p = (const int*)d_in[4];
    float* out = (float*)d_out;
    unsigned* ws = (unsigned*)d_ws;

    k_prep<<<A_GRID, 256, 0, stream>>>(x, f, e_h, e_p, y, ws);
    k_edge<<<E_GRID, 256, 0, stream>>>(x, f, e_h, e_p, ws);
    k_main<<<D_GRID, 256, 0, stream>>>(x, ws, out);
}

// Round 5
// 104.938 us; speedup vs baseline: 1.1930x; 1.0640x over previous
//
#include <hip/hip_runtime.h>
#include <math.h>

#define N_HIT  50000
#define N_TRUE 512
#define N_EDGE 40000
#define Q_MIN  0.5f

// ---- ws layout (4-byte word offsets) ----
#define W_CENTERS   512           // int[512], zeroed by k_prep block 48
#define W_SUMFC     1024
#define W_DONE_EDGE 1025
#define W_DONE_MAIN 1026
#define W_VPART     1040          // 8 float slots, stride 16 words
#define W_ZERO_LO   512
#define W_ZERO_HI   1168
#define W_BKGPART   1200          // float[32]
#define W_BKGCNT    1232          // float[32]
#define W_FCPART    2048          // uint fc_part[16][512]
#define W_CTAB      16384         // float ctab[512][12]: c0..c7, |c|^2, qc, pad,pad
#define W_HREC      32768         // float2 hrec[50000]: (|x|^2, q)

#define A_EDGE_BLOCKS 16
#define A_BKG_BLOCKS  32
#define A_GRID 49                 // +1 zero block
#define EPB (N_EDGE / A_EDGE_BLOCKS)    // 2500

#define E_GRID ((N_EDGE + 255) / 256)   // 157

#define KSPLIT 16
#define KCH    (N_TRUE / KSPLIT)        // 32
#define HPT    4
#define HCHUNK (256 * HPT)              // 1024
#define NHB    ((N_HIT + HCHUNK - 1) / HCHUNK)   // 49
#define D_DENSE (NHB * KSPLIT)          // 784
#define D_CORR  16
#define D_GRID  (D_DENSE + D_CORR)      // 800

// A: segment-max partials (LDS), bkg sums + per-hit (|x|^2,q), zero scalars
__global__ __launch_bounds__(256) void k_prep(const float* __restrict__ x,
                                              const float* __restrict__ f,
                                              const int* __restrict__ e_h,
                                              const int* __restrict__ e_p,
                                              const int* __restrict__ y,
                                              unsigned* __restrict__ ws) {
    const int b = blockIdx.x, t = threadIdx.x;
    if (b < A_EDGE_BLOCKS) {
        __shared__ unsigned lmax[N_TRUE];
        lmax[t] = 0u; lmax[t + 256] = 0u;
        __syncthreads();
        const int e0 = b * EPB;
        for (int e = e0 + t; e < e0 + EPB; e += 256)
            atomicMax(&lmax[e_p[e]], __float_as_uint(f[e_h[e]]));
        __syncthreads();
        ws[W_FCPART + b * N_TRUE + t]       = lmax[t];
        ws[W_FCPART + b * N_TRUE + t + 256] = lmax[t + 256];
    } else if (b < A_EDGE_BLOCKS + A_BKG_BLOCKS) {
        const int bb = b - A_EDGE_BLOCKS;
        float2* hrec = (float2*)(ws + W_HREC);
        float sf = 0.f, fc = 0.f;
        for (int i = bb * 256 + t; i < N_HIT; i += A_BKG_BLOCKS * 256) {
            const float4* xp = (const float4*)(x + (size_t)i * 8);
            const float4 x0 = xp[0], x1 = xp[1];
            float xi2 = x0.x * x0.x;
            xi2 = fmaf(x0.y, x0.y, xi2); xi2 = fmaf(x0.z, x0.z, xi2);
            xi2 = fmaf(x0.w, x0.w, xi2); xi2 = fmaf(x1.x, x1.x, xi2);
            xi2 = fmaf(x1.y, x1.y, xi2); xi2 = fmaf(x1.z, x1.z, xi2);
            xi2 = fmaf(x1.w, x1.w, xi2);
            const float fi = f[i];
            const float a  = atanhf(fi);
            hrec[i] = make_float2(xi2, fmaf(a, a, Q_MIN));
            if (y[i] == -1) { sf += fi; fc += 1.f; }
        }
        for (int off = 32; off; off >>= 1) {
            sf += __shfl_down(sf, off, 64);
            fc += __shfl_down(fc, off, 64);
        }
        __shared__ float r[8];
        if ((t & 63) == 0) { r[t >> 6] = sf; r[4 + (t >> 6)] = fc; }
        __syncthreads();
        if (t == 0) {
            ((float*)ws)[W_BKGPART + bb] = r[0] + r[1] + r[2] + r[3];
            ((float*)ws)[W_BKGCNT  + bb] = r[4] + r[5] + r[6] + r[7];
        }
    } else {
        for (int w = W_ZERO_LO + t; w < W_ZERO_HI; w += 256) ws[w] = 0u;
    }
}

// B: per edge — argmax-hit via partial re-reduce; last block builds center table
__global__ __launch_bounds__(256) void k_edge(const float* __restrict__ x,
                                              const float* __restrict__ f,
                                              const int* __restrict__ e_h,
                                              const int* __restrict__ e_p,
                                              unsigned* __restrict__ ws) {
    const int t = threadIdx.x;
    const int e = blockIdx.x * 256 + t;
    if (e < N_EDGE) {
        const int h = e_h[e], p = e_p[e];
        unsigned fm = 0u;
#pragma unroll
        for (int b = 0; b < A_EDGE_BLOCKS; ++b)
            fm = max(fm, ws[W_FCPART + b * N_TRUE + p]);
        if (__float_as_uint(f[h]) == fm)
            atomicMax((int*)ws + W_CENTERS + p, h);
    }
    __syncthreads();
    __shared__ int is_last;
    if (t == 0) {
        __threadfence();
        is_last = (atomicAdd(&ws[W_DONE_EDGE], 1u) == E_GRID - 1);
    }
    __syncthreads();
    if (!is_last) return;

    __threadfence();
    float local = 0.f;
    for (int p = t; p < N_TRUE; p += 256) {
        unsigned fm = 0u;
#pragma unroll
        for (int b = 0; b < A_EDGE_BLOCKS; ++b)
            fm = max(fm, ws[W_FCPART + b * N_TRUE + p]);
        local += __uint_as_float(fm);
        const int c = __hip_atomic_load((int*)ws + W_CENTERS + p,
                                        __ATOMIC_RELAXED, __HIP_MEMORY_SCOPE_AGENT);
        const float4* xp = (const float4*)(x + (size_t)c * 8);
        const float4 x0 = xp[0], x1 = xp[1];
        float ck2 = x0.x * x0.x;
        ck2 = fmaf(x0.y, x0.y, ck2); ck2 = fmaf(x0.z, x0.z, ck2);
        ck2 = fmaf(x0.w, x0.w, ck2); ck2 = fmaf(x1.x, x1.x, ck2);
        ck2 = fmaf(x1.y, x1.y, ck2); ck2 = fmaf(x1.z, x1.z, ck2);
        ck2 = fmaf(x1.w, x1.w, ck2);
        const float a = atanhf(f[c]);
        float* line = (float*)ws + W_CTAB + (size_t)p * 12;
        ((float4*)line)[0] = x0;
        ((float4*)line)[1] = x1;
        line[8] = ck2;
        line[9] = fmaf(a, a, Q_MIN);
    }
    for (int off = 32; off; off >>= 1) local += __shfl_down(local, off, 64);
    __shared__ float r[4];
    if ((t & 63) == 0) r[t >> 6] = local;
    __syncthreads();
    if (t == 0) ((float*)ws)[W_SUMFC] = r[0] + r[1] + r[2] + r[3];
}

// C: dense hinge term (no mask) + sparse edge correction + fused finalize
__global__ __launch_bounds__(256, 4) void k_main(const float* __restrict__ x,
                                                 const int* __restrict__ e_h,
                                                 const int* __restrict__ e_p,
                                                 unsigned* __restrict__ ws,
                                                 float* __restrict__ out) {
    const int t = threadIdx.x;
    const int b = blockIdx.x;
    const float2* __restrict__ hrec = (const float2*)(ws + W_HREC);
    float vout = 0.f;

    if (b < D_DENSE) {
        const int hb = b >> 4;          // 0..48
        const int kb = b & 15;          // 0..15
        __shared__ float ct[KCH * 12];
        for (int w = t; w < KCH * 12; w += 256)
            ct[w] = ((const float*)ws)[W_CTAB + kb * KCH * 12 + w];
        __syncthreads();

        float4 xr0[HPT], xr1[HPT];
        float  xi2[HPT], qi[HPT], acc[HPT];
#pragma unroll
        for (int j = 0; j < HPT; ++j) {
            const int i = hb * HCHUNK + j * 256 + t;
            const bool valid = (i < N_HIT);
            const int  ic = valid ? i : 0;
            const float4* xp = (const float4*)(x + (size_t)ic * 8);
            xr0[j] = xp[0]; xr1[j] = xp[1];
            const float2 hq = hrec[ic];
            xi2[j] = hq.x;
            qi[j]  = valid ? hq.y : 0.f;
            acc[j] = 0.f;
        }
#pragma unroll
        for (int k2 = 0; k2 < KCH; ++k2) {
            const float4 c0  = *(const float4*)(ct + 12 * k2);
            const float4 c1  = *(const float4*)(ct + 12 * k2 + 4);
            const float  ck2 = ct[12 * k2 + 8];
            const float  qck = ct[12 * k2 + 9];
#pragma unroll
            for (int j = 0; j < HPT; ++j) {
                float dot = xr0[j].x * c0.x;
                dot = fmaf(xr0[j].y, c0.y, dot); dot = fmaf(xr0[j].z, c0.z, dot);
                dot = fmaf(xr0[j].w, c0.w, dot); dot = fmaf(xr1[j].x, c1.x, dot);
                dot = fmaf(xr1[j].y, c1.y, dot); dot = fmaf(xr1[j].z, c1.z, dot);
                dot = fmaf(xr1[j].w, c1.w, dot);
                const float dist = fmaf(-2.f, dot, xi2[j] + ck2);
                const float rep  = fmaxf(1.f - dist, 0.f);
                acc[j] = fmaf(rep, qck, acc[j]);
            }
        }
#pragma unroll
        for (int j = 0; j < HPT; ++j) vout = fmaf(acc[j], qi[j], vout);
    } else {
        // sparse correction: member pairs get (dist - hinge) instead of hinge
        const int cb = b - D_DENSE;
        const float* __restrict__ ctab = (const float*)ws + W_CTAB;
        for (int e = cb * 256 + t; e < N_EDGE; e += D_CORR * 256) {
            const int h = e_h[e], p = e_p[e];
            const float2 hq = hrec[h];
            const float4* xp = (const float4*)(x + (size_t)h * 8);
            const float4 a0 = xp[0], a1 = xp[1];
            const float* line = ctab + (size_t)p * 12;
            const float4 c0 = *(const float4*)line;
            const float4 c1 = *(const float4*)(line + 4);
            const float ck2 = line[8], qck = line[9];
            float dot = a0.x * c0.x;
            dot = fmaf(a0.y, c0.y, dot); dot = fmaf(a0.z, c0.z, dot);
            dot = fmaf(a0.w, c0.w, dot); dot = fmaf(a1.x, c1.x, dot);
            dot = fmaf(a1.y, c1.y, dot); dot = fmaf(a1.z, c1.z, dot);
            dot = fmaf(a1.w, c1.w, dot);
            const float dist  = fmaf(-2.f, dot, hq.x + ck2);
            const float hinge = fmaxf(1.f - dist, 0.f);
            vout = fmaf(hq.y * qck, dist - hinge, vout);
        }
    }

    for (int off = 32; off; off >>= 1) vout += __shfl_down(vout, off, 64);
    __shared__ float r[4];
    if ((t & 63) == 0) r[t >> 6] = vout;
    __syncthreads();
    if (t == 0) {
        atomicAdd((float*)ws + W_VPART + (b & 7) * 16, r[0] + r[1] + r[2] + r[3]);
        __threadfence();
        const unsigned c = atomicAdd(&ws[W_DONE_MAIN], 1u);
        if (c == D_GRID - 1) {
            __threadfence();
            float vs = 0.f;
            for (int s = 0; s < 8; ++s)
                vs += atomicAdd((float*)ws + W_VPART + s * 16, 0.0f);
            float sum_bkg = 0.f, nb = 0.f;
            for (int s = 0; s < A_BKG_BLOCKS; ++s) {
                sum_bkg += __hip_atomic_load((const float*)ws + W_BKGPART + s,
                                             __ATOMIC_RELAXED, __HIP_MEMORY_SCOPE_AGENT);
                nb      += __hip_atomic_load((const float*)ws + W_BKGCNT + s,
                                             __ATOMIC_RELAXED, __HIP_MEMORY_SCOPE_AGENT);
            }
            const float sum_fc = __hip_atomic_load((const float*)ws + W_SUMFC,
                                                   __ATOMIC_RELAXED, __HIP_MEMORY_SCOPE_AGENT);
            out[0] = (1.f - sum_fc / (float)N_TRUE) + sum_bkg / nb;   // S_B = 1
            out[1] = vs / (float)N_HIT;
        }
    }
}

extern "C" void kernel_launch(void* const* d_in, const int* in_sizes, int n_in,
                              void* d_out, int out_size, void* d_ws, size_t ws_size,
                              hipStream_t stream) {
    const float* x   = (const float*)d_in[0];
    const float* f   = (const float*)d_in[1];
    const int*   y   = (const int*)d_in[2];
    const int*   e_h = (const int*)d_in[3];
    const int*   e_p = (const int*)d_in[4];
    float* out = (float*)d_out;
    unsigned* ws = (unsigned*)d_ws;

    k_prep<<<A_GRID, 256, 0, stream>>>(x, f, e_h, e_p, y, ws);
    k_edge<<<E_GRID, 256, 0, stream>>>(x, f, e_h, e_p, ws);
    k_main<<<D_GRID, 256, 0, stream>>>(x, e_h, e_p, ws, out);
}